// Round 7
// baseline (722.392 us; speedup 1.0000x reference)
//
#include <hip/hip_runtime.h>

typedef unsigned short u16;
typedef unsigned int   u32;
typedef __attribute__((ext_vector_type(8))) short short8;   // 8 bf16 (4 VGPR)
typedef __attribute__((ext_vector_type(4))) float f32x4;

#define DEV static __device__ __forceinline__
#define LGKM0 asm volatile("s_waitcnt lgkmcnt(0)" ::: "memory")
#define VMCNT(n) asm volatile("s_waitcnt vmcnt(" #n ")" ::: "memory")
#define BAR   __builtin_amdgcn_s_barrier()
#define SCH0  __builtin_amdgcn_sched_barrier(0)

DEV u16 f2bf(float f){                       // f32 -> bf16 RNE
  union { float f; u32 u; } v; v.f = f;
  u32 u = v.u;
  u += 0x7fffu + ((u >> 16) & 1u);
  return (u16)(u >> 16);
}
DEV float sigmoidf_(float x){ return 1.f / (1.f + __expf(-x)); }
DEV float tanh_fast(float x){ float e = __expf(2.f * x); return 1.f - 2.f / (e + 1.f); }

DEV void gload16(const void* g, void* l){    // async global->LDS, dest = uniform base + lane*16
  __builtin_amdgcn_global_load_lds(
      (const __attribute__((address_space(1))) void*)g,
      (__attribute__((address_space(3))) void*)l, 16, 0, 0);
}
DEV f32x4 mfma16(short8 a, short8 b, f32x4 c){
  return __builtin_amdgcn_mfma_f32_16x16x32_bf16(a, b, c, 0, 0, 0);
}
// 8 f32 -> short8 bf16 via v_cvt_pk_bf16_f32 (RNE; HW-verified R5/R6 absmax)
DEV short8 cvt8(float4 lo, float4 hi){
  union { u32 w[4]; short8 s; } r;
  asm("v_cvt_pk_bf16_f32 %0, %1, %2" : "=v"(r.w[0]) : "v"(lo.x), "v"(lo.y));
  asm("v_cvt_pk_bf16_f32 %0, %1, %2" : "=v"(r.w[1]) : "v"(lo.z), "v"(lo.w));
  asm("v_cvt_pk_bf16_f32 %0, %1, %2" : "=v"(r.w[2]) : "v"(hi.x), "v"(hi.y));
  asm("v_cvt_pk_bf16_f32 %0, %1, %2" : "=v"(r.w[3]) : "v"(hi.z), "v"(hi.w));
  return r.s;
}

// ---------------------------------------------------------------------------
// transpose + f32->bf16: src (K x N) f32  ->  dst (N x K) bf16
__global__ __launch_bounds__(256) void k_transpose_cvt(
    const float* __restrict__ src, u16* __restrict__ dst, int K, int N){
  __shared__ u16 t[64][72];
  int k0 = blockIdx.x << 6, n0 = blockIdx.y << 6;
  int tid = threadIdx.x;
  int r = tid >> 2, c0 = (tid & 3) << 4;
#pragma unroll
  for (int i = 0; i < 4; i++){
    float4 v = *(const float4*)&src[(size_t)(k0 + r) * N + n0 + c0 + i * 4];
    *(u32*)&t[r][c0 + i * 4 + 0] = (u32)f2bf(v.x) | ((u32)f2bf(v.y) << 16);
    *(u32*)&t[r][c0 + i * 4 + 2] = (u32)f2bf(v.z) | ((u32)f2bf(v.w) << 16);
  }
  __syncthreads();
  int n = tid >> 2, cc = (tid & 3) << 4;
  union { u16 s[16]; uint4 q[2]; } pk;
#pragma unroll
  for (int i = 0; i < 16; i++) pk.s[i] = t[cc + i][n];
  uint4* o = (uint4*)(dst + (size_t)(n0 + n) * K + k0 + cc);
  o[0] = pk.q[0]; o[1] = pk.q[1];
}

// ---------------------------------------------------------------------------
// q[b,u] = prevState[b,:] @ Ww[:,u] + bw[u] + bu[u]
__global__ __launch_bounds__(512) void k_q(
    const float* __restrict__ ps, const float* __restrict__ Ww,
    const float* __restrict__ bw, const float* __restrict__ bu,
    float* __restrict__ q){
  __shared__ float psl[16][512];
  int b0 = blockIdx.x << 4;
  int tid = threadIdx.x;
#pragma unroll
  for (int i = 0; i < 16; i++) psl[i][tid] = ps[(size_t)(b0 + i) * 512 + tid];
  __syncthreads();
  float acc[16];
#pragma unroll
  for (int i = 0; i < 16; i++) acc[i] = 0.f;
  for (int j = 0; j < 512; j++){
    float w = Ww[(size_t)j * 512 + tid];
#pragma unroll
    for (int i = 0; i < 16; i++) acc[i] = fmaf(psl[i][j], w, acc[i]);
  }
  float bias = bw[tid] + bu[tid];
#pragma unroll
  for (int i = 0; i < 16; i++) q[(size_t)(b0 + i) * 512 + tid] = acc[i] + bias;
}

// ---------------------------------------------------------------------------
__global__ __launch_bounds__(256) void k_gather(
    const int* __restrict__ tok, const float* __restrict__ emb, u16* __restrict__ xbf){
  int b = blockIdx.x, e = threadIdx.x;
  int t = tok[b];
  xbf[(size_t)b * 2304 + 2048 + e] = f2bf(emb[(size_t)t * 256 + e]);
}

// ---------------------------------------------------------------------------
__global__ __launch_bounds__(512) void k_bnprep(
    const float* __restrict__ gamma, const float* __restrict__ beta,
    const float* __restrict__ mmean, const float* __restrict__ mvar,
    const float* __restrict__ b1, float* __restrict__ bns, float* __restrict__ bno){
  int u = threadIdx.x;
  float sc = gamma[u] * rsqrtf(mvar[u] + 1e-3f);
  bns[u] = sc;
  bno[u] = (b1[u] - mmean[u]) * sc + beta[u];
}

// ---------------------------------------------------------------------------
// score GEMM v5 — counted vmcnt, NEVER drained (T4). A issued 2 tiles ahead
// (cover ~1.5 iters >= HBM latency); B (L2-hot WuT) 1 tile ahead.
// 256 thr / 4 waves (2wm x 2wn), tile 128x128, wave tile 64x64.
// Invariant entering ITER(t): buf t&1 ready; outstanding (oldest first):
//   A(t+1)[8], B(t+1)[4], A(t+2)[8]. A(k) lives in rA if k odd, rB if k even.
// ITER(t): BAR; MFMA(t); vmcnt(12)->A(t+1); cvtWrite; vmcnt(8)->B(t+1);
//          LGKM0; BAR; issue B(t+2), A(t+3).
__global__ __launch_bounds__(256, 2) void k_score(
    const float* __restrict__ fm, const u16* __restrict__ WuT,
    const float* __restrict__ q, const float* __restrict__ Wv,
    float* __restrict__ sp){
  __shared__ __align__(16) u16 Ab[2][128 * 64];   // 16 KB each
  __shared__ __align__(16) u16 Bb[2][128 * 64];   // 16 KB each
  __shared__ float qsl[2][128];
  __shared__ float wvsl[128];
  __shared__ float part[128][2];

  int bid = blockIdx.x;
  // same-XCD sibling grouping (R6-proven: FETCH 555->314 MB)
  int slab = ((bid >> 5) << 3) | (bid & 7);
  int nblk = (bid >> 3) & 3;
  int n0 = nblk << 7;
  size_t gm0 = (size_t)slab << 7;                 // 128 rows (= 2 batches)

  int tid = threadIdx.x, wid = tid >> 6, lane = tid & 63;
  int wm = wid >> 1, wn = wid & 1;
  int l15 = lane & 15, g = lane >> 4;

  qsl[tid >> 7][tid & 127] = q[(size_t)((slab << 1) + (tid >> 7)) * 512 + n0 + (tid & 127)];
  if (tid < 128) wvsl[tid] = Wv[n0 + tid];

  f32x4 acc[4][4];
#pragma unroll
  for (int i = 0; i < 4; i++)
#pragma unroll
    for (int j = 0; j < 4; j++) acc[i][j] = (f32x4){0.f, 0.f, 0.f, 0.f};

  // ---- staging geometry ----
  int arow = tid >> 1, acol = (tid & 1) << 5;     // A: row 0..127, col base 0/32
  const float* gaBase = fm + (gm0 + arow) * 2048 + acol;
  int ac0 = (tid & 1) << 2;                       // chunk base 0 or 4

  auto issueA = [&](int t, float4* r){            // 8 float4 -> regs (HBM)
    const float* ga = gaBase + (t << 6);
#pragma unroll
    for (int i = 0; i < 8; i++) r[i] = *(const float4*)(ga + i * 4);
  };
  auto cvtWriteA = [&](float4* r, int buf){       // cvt + swizzled ds_write
#pragma unroll
    for (int i = 0; i < 4; i++){
      int c = ac0 + i;
      int sl = c ^ (arow & 7);
      *(short8*)&Ab[buf][arow * 64 + sl * 8] = cvt8(r[2 * i], r[2 * i + 1]);
    }
  };
  auto gloadB = [&](int t, int buf){              // 4 gload16/thread (L2-hot)
    int k0 = t << 6;
#pragma unroll
    for (int i = 0; i < 4; i++){
      int p = (i << 8) + tid;                     // chunk 0..1023
      int row = p >> 3, sl = p & 7;
      int sl2 = sl ^ (row & 7);
      gload16(WuT + (size_t)(n0 + row) * 2048 + k0 + sl2 * 8,
              (char*)Bb[buf] + (size_t)((i << 8) + (wid << 6)) * 16);
    }
  };
  auto computeStep = [&](int buf){
#pragma unroll
    for (int kh = 0; kh < 2; kh++){
      short8 af[4], bfr[4];
#pragma unroll
      for (int mi = 0; mi < 4; mi++){
        int r = wm * 64 + mi * 16 + l15;
        af[mi] = *(const short8*)&Ab[buf][r * 64 + (((kh << 2) + g) ^ (r & 7)) * 8];
      }
#pragma unroll
      for (int ni = 0; ni < 4; ni++){
        int r = wn * 64 + ni * 16 + l15;
        bfr[ni] = *(const short8*)&Bb[buf][r * 64 + (((kh << 2) + g) ^ (r & 7)) * 8];
      }
#pragma unroll
      for (int mi = 0; mi < 4; mi++)
#pragma unroll
        for (int ni = 0; ni < 4; ni++)
          acc[mi][ni] = mfma16(af[mi], bfr[ni], acc[mi][ni]);
    }
  };

  float4 rA[8], rB[8];

  // ---- prologue: establish the steady-state invariant for ITER(0)
  gloadB(0, 0);          // B(0)            [ 4 outstanding]
  issueA(0, rB);         // A(0) -> rB      [12]
  issueA(1, rA);         // A(1) -> rA      [20]
  gloadB(1, 1);          // B(1)            [24]
  VMCNT(12); SCH0;       // B(0), A(0) landed
  cvtWriteA(rB, 0);
  issueA(2, rB);         // A(2) -> rB; outstanding: A(1)+B(1)+A(2) = 20
  LGKM0; SCH0;

#define K_ITER(T, RCUR, WA, WB, DOB, DOA) do{                      \
    BAR; SCH0;                                                     \
    computeStep((T) & 1);                                          \
    WA; SCH0;                       /* A(T+1) landed */            \
    cvtWriteA(RCUR, ((T) + 1) & 1);                                \
    WB; SCH0;                       /* B(T+1) landed */            \
    LGKM0; SCH0;                                                   \
    BAR;                                                           \
    if (DOB) gloadB((T) + 2, (T) & 1);                             \
    if (DOA) issueA((T) + 3, RCUR);                                \
  } while(0)

  for (int t = 0; t < 28; t += 2){
    K_ITER(t,     rA, VMCNT(12), VMCNT(8), true, true);
    K_ITER(t + 1, rB, VMCNT(12), VMCNT(8), true, true);
  }
  K_ITER(28, rA, VMCNT(12), VMCNT(8), true,  true);   // issues B(30), A(31)
  K_ITER(29, rB, VMCNT(12), VMCNT(8), true,  false);  // issues B(31)
  K_ITER(30, rA, VMCNT(4),  VMCNT(0), false, false);  // tail counts
  BAR; SCH0;
  computeStep(1);                                      // t = 31
#undef K_ITER

  // ---- epilogue: tanh(S1+q)*Wv, reduce over this block's 128 cols
#pragma unroll
  for (int mi = 0; mi < 4; mi++)
#pragma unroll
    for (int j = 0; j < 4; j++){
      float s = 0.f;
#pragma unroll
      for (int ni = 0; ni < 4; ni++){
        int ul = wn * 64 + ni * 16 + l15;
        s += tanh_fast(acc[mi][ni][j] + qsl[wm][ul]) * wvsl[ul];
      }
      s += __shfl_xor(s, 1);
      s += __shfl_xor(s, 2);
      s += __shfl_xor(s, 4);
      s += __shfl_xor(s, 8);
      if (l15 == 0)
        part[wm * 64 + mi * 16 + g * 4 + j][wn] = s;
    }
  LGKM0; BAR;
  if (tid < 128)
    sp[(size_t)nblk * 65536 + gm0 + tid] = part[tid][0] + part[tid][1];
}

// ---------------------------------------------------------------------------
// softmax over L=64 per b; attn -> d_out (f32)
__global__ __launch_bounds__(64) void k_softmax(
    const float* __restrict__ sp, float* __restrict__ attn_out){
  int b = blockIdx.x, l = threadIdx.x;
  size_t m = (size_t)b * 64 + l;
  float s = sp[m] + sp[65536 + m] + sp[2 * 65536 + m] + sp[3 * 65536 + m];
  float mx = s;
#pragma unroll
  for (int k = 32; k >= 1; k >>= 1) mx = fmaxf(mx, __shfl_xor(mx, k));
  float e = __expf(s - mx);
  float sum = e;
#pragma unroll
  for (int k = 32; k >= 1; k >>= 1) sum += __shfl_xor(sum, k);
  attn_out[m] = e / sum;
}

// ---------------------------------------------------------------------------
// ctx[b,:] = sum_l attn[b,l] * FM[b,l,:]  -> x_bf16[b, 0:2048]
__global__ __launch_bounds__(512) void k_ctx(
    const float* __restrict__ fm, const float* __restrict__ attn,
    u16* __restrict__ xbf){
  __shared__ float as_[64];
  int b = blockIdx.x, tid = threadIdx.x;
  if (tid < 64) as_[tid] = attn[(size_t)b * 64 + tid];
  __syncthreads();
  const float4* fmr = (const float4*)(fm + (size_t)b * (64 * 2048));
  float4 cx = {0.f, 0.f, 0.f, 0.f};
#pragma unroll 4
  for (int l = 0; l < 64; l++){
    float a = as_[l];
    float4 v = fmr[(size_t)l * 512 + tid];
    cx.x = fmaf(a, v.x, cx.x); cx.y = fmaf(a, v.y, cx.y);
    cx.z = fmaf(a, v.z, cx.z); cx.w = fmaf(a, v.w, cx.w);
  }
  uint2 o;
  o.x = (u32)f2bf(cx.x) | ((u32)f2bf(cx.y) << 16);
  o.y = (u32)f2bf(cx.z) | ((u32)f2bf(cx.w) << 16);
  *(uint2*)&xbf[(size_t)b * 2304 + tid * 4] = o;
}

// ---------------------------------------------------------------------------
// generic GEMM: C(MxN) = A(MxK bf16) @ Bt(NxK bf16)^T, epilogue scale/offset
template<bool OBF>
__global__ __launch_bounds__(512) void k_gemm(
    const u16* __restrict__ A, const u16* __restrict__ Bt,
    const float* __restrict__ scale, const float* __restrict__ off,
    void* __restrict__ Cout, int K, int N){
  __shared__ __align__(16) u16 Alds[2][128 * 64];
  __shared__ __align__(16) u16 Blds[2][128 * 64];
  int n0 = blockIdx.x << 7, m0 = blockIdx.y << 7;
  int tid = threadIdx.x, wid = tid >> 6, lane = tid & 63;
  int wm = wid >> 2, wn = wid & 3;

  f32x4 acc[4][2];
#pragma unroll
  for (int i = 0; i < 4; i++)
#pragma unroll
    for (int j = 0; j < 2; j++) acc[i][j] = (f32x4){0.f, 0.f, 0.f, 0.f};

  auto stage = [&](int s, int k0){
#pragma unroll
    for (int i = 0; i < 2; i++){
      int p = ((wid * 2 + i) << 6) + lane;
      int row = p >> 3, sl = p & 7, sl2 = sl ^ (row & 7);
      gload16(A  + (size_t)(m0 + row) * K + k0 + sl2 * 8,
              (char*)Alds[s] + (size_t)(wid * 2 + i) * 1024);
      gload16(Bt + (size_t)(n0 + row) * K + k0 + sl2 * 8,
              (char*)Blds[s] + (size_t)(wid * 2 + i) * 1024);
    }
  };

  int nk = K >> 6;
  stage(0, 0);
  __syncthreads();
  int cur = 0;
  for (int t = 0; t < nk; t++){
    if (t + 1 < nk) stage(cur ^ 1, (t + 1) << 6);
#pragma unroll
    for (int kh = 0; kh < 2; kh++){
      short8 af[4], bfr[2];
#pragma unroll
      for (int mi = 0; mi < 4; mi++){
        int r = wm * 64 + mi * 16 + (lane & 15);
        af[mi] = *(const short8*)&Alds[cur][r * 64 + (((kh << 2) + (lane >> 4)) ^ (r & 7)) * 8];
      }
#pragma unroll
      for (int ni = 0; ni < 2; ni++){
        int r = wn * 32 + ni * 16 + (lane & 15);
        bfr[ni] = *(const short8*)&Blds[cur][r * 64 + (((kh << 2) + (lane >> 4)) ^ (r & 7)) * 8];
      }
#pragma unroll
      for (int mi = 0; mi < 4; mi++)
#pragma unroll
        for (int ni = 0; ni < 2; ni++)
          acc[mi][ni] = mfma16(af[mi], bfr[ni], acc[mi][ni]);
    }
    __syncthreads();
    cur ^= 1;
  }
#pragma unroll
  for (int ni = 0; ni < 2; ni++){
    int n = n0 + wn * 32 + ni * 16 + (lane & 15);
    float sc = scale ? scale[n] : 1.f;
    float of = off ? off[n] : 0.f;
#pragma unroll
    for (int mi = 0; mi < 4; mi++)
#pragma unroll
      for (int j = 0; j < 4; j++){
        int m = m0 + wm * 64 + mi * 16 + (lane >> 4) * 4 + j;
        float v = acc[mi][ni][j] * sc + of;
        if (OBF) ((u16*)Cout)[(size_t)m * N + n] = f2bf(v);
        else     ((float*)Cout)[(size_t)m * N + n] = v;
      }
  }
}

// ---------------------------------------------------------------------------
__global__ __launch_bounds__(512) void k_gates(
    const float* __restrict__ xg, const float* __restrict__ gru_b,
    float* __restrict__ hout, u16* __restrict__ hbf){
  int b = blockIdx.x, u = threadIdx.x;
  const float* rg = gru_b + 1536;
  size_t base = (size_t)b * 1536;
  float z  = sigmoidf_(xg[base + u]        + rg[u]);
  float r  = sigmoidf_(xg[base + 512 + u]  + rg[512 + u]);
  float hh = tanh_fast(xg[base + 1024 + u] + r * rg[1024 + u]);
  float h = (1.f - z) * hh;
  hout[(size_t)b * 512 + u] = h;
  hbf[(size_t)b * 512 + u] = f2bf(h);
}

// ---------------------------------------------------------------------------
extern "C" void kernel_launch(void* const* d_in, const int* in_sizes, int n_in,
                              void* d_out, int out_size, void* d_ws, size_t ws_size,
                              hipStream_t stream){
  const int*   tok   = (const int*)  d_in[0];
  const float* fm    = (const float*)d_in[1];
  const float* ps    = (const float*)d_in[2];
  const float* emb   = (const float*)d_in[3];
  const float* Wu    = (const float*)d_in[4];
  const float* bu    = (const float*)d_in[5];
  const float* Ww    = (const float*)d_in[6];
  const float* bw    = (const float*)d_in[7];
  const float* Wv    = (const float*)d_in[8];
  // d_in[9] = bv: softmax-invariant, unused. d_in[11] = gru_rk: dead in reference.
  const float* gru_k = (const float*)d_in[10];
  const float* gru_b = (const float*)d_in[12];
  const float* W1    = (const float*)d_in[13];
  const float* b1    = (const float*)d_in[14];
  const float* gamma = (const float*)d_in[15];
  const float* beta  = (const float*)d_in[16];
  const float* mmean = (const float*)d_in[17];
  const float* mvar  = (const float*)d_in[18];
  const float* W2    = (const float*)d_in[19];
  const float* b2    = (const float*)d_in[20];

  float* logits = (float*)d_out;                     // 1024 x 32000
  float* hout   = (float*)d_out + 32768000;          // 1024 x 512
  float* attn   = (float*)d_out + 33292288;          // 1024 x 64

  char* ws = (char*)d_ws;
  u16*   WuT = (u16*)  (ws + 0);          // 512  x 2048 bf16
  u16*   gkT = (u16*)  (ws + 2097152);    // 1536 x 2304 bf16
  u16*   W2T = (u16*)  (ws + 9175040);    // 32000x 512  bf16
  u16*   W1T = (u16*)  (ws + 41943040);   // 512  x 512  bf16
  float* qws = (float*)(ws + 42467328);   // 1024 x 512  f32
  u16*   xbf = (u16*)  (ws + 44564480);   // 1024 x 2304 bf16
  float* xg  = (float*)(ws + 49283072);   // 1024 x 1536 f32
  u16*   hbf = (u16*)  (ws + 55574528);   // 1024 x 512  bf16
  u16*   ybf = (u16*)  (ws + 56623104);   // 1024 x 512  bf16
  float* bns = (float*)(ws + 57671680);   // 512 f32
  float* bno = (float*)(ws + 57673728);   // 512 f32
  float* sp  = xg;  // 4 x 65536 f32 aliases xg (consumed before xg written)

  k_transpose_cvt<<<dim3(32, 8),  256, 0, stream>>>(Wu,    WuT, 2048, 512);
  k_transpose_cvt<<<dim3(36, 24), 256, 0, stream>>>(gru_k, gkT, 2304, 1536);
  k_transpose_cvt<<<dim3(8, 500), 256, 0, stream>>>(W2,    W2T, 512,  32000);
  k_transpose_cvt<<<dim3(8, 8),   256, 0, stream>>>(W1,    W1T, 512,  512);
  k_q<<<64, 512, 0, stream>>>(ps, Ww, bw, bu, qws);
  k_gather<<<1024, 256, 0, stream>>>(tok, emb, xbf);
  k_bnprep<<<1, 512, 0, stream>>>(gamma, beta, mmean, mvar, b1, bns, bno);
  // attention: counted-vmcnt pipelined score GEMM -> softmax -> ctx
  k_score<<<2048, 256, 0, stream>>>(fm, WuT, qws, Wv, sp);
  k_softmax<<<1024, 64, 0, stream>>>(sp, attn);
  k_ctx<<<1024, 512, 0, stream>>>(fm, attn, xbf);
  // xg = x @ gru_k + gru_b[0]
  k_gemm<false><<<dim3(12, 8), 512, 0, stream>>>(xbf, gkT, nullptr, gru_b, xg, 2304, 1536);
  k_gates<<<1024, 512, 0, stream>>>(xg, gru_b, hout, hbf);
  k_gemm<true><<<dim3(4, 8), 512, 0, stream>>>(hbf, W1T, bns, bno, ybf, 512, 512);
  k_gemm<false><<<dim3(250, 8), 512, 0, stream>>>(ybf, W2T, nullptr, b2, logits, 512, 32000);
}

// Round 8
// 617.145 us; speedup vs baseline: 1.1705x; 1.1705x over previous
//
#include <hip/hip_runtime.h>

typedef unsigned short u16;
typedef unsigned int   u32;
typedef __attribute__((ext_vector_type(8))) short short8;   // 8 bf16 (4 VGPR)
typedef __attribute__((ext_vector_type(4))) float f32x4;

#define DEV static __device__ __forceinline__

DEV u16 f2bf(float f){                       // f32 -> bf16 RNE
  union { float f; u32 u; } v; v.f = f;
  u32 u = v.u;
  u += 0x7fffu + ((u >> 16) & 1u);
  return (u16)(u >> 16);
}
DEV float sigmoidf_(float x){ return 1.f / (1.f + __expf(-x)); }
DEV float tanh_fast(float x){ float e = __expf(2.f * x); return 1.f - 2.f / (e + 1.f); }

DEV void gload16(const void* g, void* l){    // async global->LDS, dest = uniform base + lane*16
  __builtin_amdgcn_global_load_lds(
      (const __attribute__((address_space(1))) void*)g,
      (__attribute__((address_space(3))) void*)l, 16, 0, 0);
}
DEV f32x4 mfma16(short8 a, short8 b, f32x4 c){
  return __builtin_amdgcn_mfma_f32_16x16x32_bf16(a, b, c, 0, 0, 0);
}

// ---------------------------------------------------------------------------
// transpose + f32->bf16: src (K x N) f32  ->  dst (N x K) bf16
__global__ __launch_bounds__(256) void k_transpose_cvt(
    const float* __restrict__ src, u16* __restrict__ dst, int K, int N){
  __shared__ u16 t[64][72];
  int k0 = blockIdx.x << 6, n0 = blockIdx.y << 6;
  int tid = threadIdx.x;
  int r = tid >> 2, c0 = (tid & 3) << 4;
#pragma unroll
  for (int i = 0; i < 4; i++){
    float4 v = *(const float4*)&src[(size_t)(k0 + r) * N + n0 + c0 + i * 4];
    *(u32*)&t[r][c0 + i * 4 + 0] = (u32)f2bf(v.x) | ((u32)f2bf(v.y) << 16);
    *(u32*)&t[r][c0 + i * 4 + 2] = (u32)f2bf(v.z) | ((u32)f2bf(v.w) << 16);
  }
  __syncthreads();
  int n = tid >> 2, cc = (tid & 3) << 4;
  union { u16 s[16]; uint4 q[2]; } pk;
#pragma unroll
  for (int i = 0; i < 16; i++) pk.s[i] = t[cc + i][n];
  uint4* o = (uint4*)(dst + (size_t)(n0 + n) * K + k0 + cc);
  o[0] = pk.q[0]; o[1] = pk.q[1];
}

// ---------------------------------------------------------------------------
// q[b,u] = prevState[b,:] @ Ww[:,u] + bw[u] + bu[u]
__global__ __launch_bounds__(512) void k_q(
    const float* __restrict__ ps, const float* __restrict__ Ww,
    const float* __restrict__ bw, const float* __restrict__ bu,
    float* __restrict__ q){
  __shared__ float psl[16][512];
  int b0 = blockIdx.x << 4;
  int tid = threadIdx.x;
#pragma unroll
  for (int i = 0; i < 16; i++) psl[i][tid] = ps[(size_t)(b0 + i) * 512 + tid];
  __syncthreads();
  float acc[16];
#pragma unroll
  for (int i = 0; i < 16; i++) acc[i] = 0.f;
  for (int j = 0; j < 512; j++){
    float w = Ww[(size_t)j * 512 + tid];
#pragma unroll
    for (int i = 0; i < 16; i++) acc[i] = fmaf(psl[i][j], w, acc[i]);
  }
  float bias = bw[tid] + bu[tid];
#pragma unroll
  for (int i = 0; i < 16; i++) q[(size_t)(b0 + i) * 512 + tid] = acc[i] + bias;
}

// ---------------------------------------------------------------------------
__global__ __launch_bounds__(256) void k_gather(
    const int* __restrict__ tok, const float* __restrict__ emb, u16* __restrict__ xbf){
  int b = blockIdx.x, e = threadIdx.x;
  int t = tok[b];
  xbf[(size_t)b * 2304 + 2048 + e] = f2bf(emb[(size_t)t * 256 + e]);
}

// ---------------------------------------------------------------------------
__global__ __launch_bounds__(512) void k_bnprep(
    const float* __restrict__ gamma, const float* __restrict__ beta,
    const float* __restrict__ mmean, const float* __restrict__ mvar,
    const float* __restrict__ b1, float* __restrict__ bns, float* __restrict__ bno){
  int u = threadIdx.x;
  float sc = gamma[u] * rsqrtf(mvar[u] + 1e-3f);
  bns[u] = sc;
  bno[u] = (b1[u] - mmean[u]) * sc + beta[u];
}

// ---------------------------------------------------------------------------
// score+softmax v6 — BYTE-MINIMAL tile: 128M x 512N (FULL N) per block.
// Delivered bytes: A (FM f32) 536 MB read EXACTLY once; B (WuT, L2-resident)
// 2 MB x 512 blocks = 1 GB; total 1.55 GB vs R6/R7's 3 GB. [R2..R7 all hit
// ~7 TB/s aggregate delivery regardless of schedule -> bytes are the lever.]
// 8 waves, wave-tile 128x64 (acc 8x4 f32x4 = 128 AGPR, distinct B-slice per
// wave -> no B duplication). A: coalesced f32 reg-stage -> cvt_pk -> swizzled
// ds_write, dbuf, one barrier/step. B: direct-from-L2 16B frags (16 lines/
// instr). Epilogue: tanh+Wv, in-block softmax over both batches -> attn.
__global__ __launch_bounds__(512, 2) void k_score(
    const float* __restrict__ fm, const u16* __restrict__ WuT,
    const float* __restrict__ q, const float* __restrict__ Wv,
    float* __restrict__ attn_out){
  __shared__ __align__(16) u16 Ab[2][128 * 64];   // 16 KB each
  __shared__ float qsl[2][512];
  __shared__ float wvsl[512];
  __shared__ float part[128][8];

  int bid = blockIdx.x;
  size_t gm0 = (size_t)bid << 7;                  // 128 rows = batches 2b,2b+1
  int tid = threadIdx.x, wid = tid >> 6, lane = tid & 63;
  int l15 = lane & 15, g = lane >> 4;

  qsl[0][tid] = q[(size_t)(bid * 2) * 512 + tid];
  qsl[1][tid] = q[(size_t)(bid * 2 + 1) * 512 + tid];
  wvsl[tid] = Wv[tid];

  f32x4 acc[8][4];
#pragma unroll
  for (int i = 0; i < 8; i++)
#pragma unroll
    for (int j = 0; j < 4; j++) acc[i][j] = (f32x4){0.f, 0.f, 0.f, 0.f};

  // ---- A staging (coalesced): load i, thread tid -> flat chunk i*512+tid;
  // row = chunk>>4 (= i*32 + tid>>4), 16B col-chunk c4 = tid&15.
  int c4 = tid & 15, r0 = tid >> 4;
  const float* gaBase = fm + (gm0 + r0) * 2048 + c4 * 4;
  int au = c4 >> 1, ah = (c4 & 1) * 4;            // LDS unit + half offset (u16)

  auto issueA = [&](int t, float4* r){
    const float* ga = gaBase + (t << 6);
#pragma unroll
    for (int i = 0; i < 4; i++)
      r[i] = *(const float4*)(ga + (size_t)i * 32 * 2048);
  };
  auto cvtWriteA = [&](float4* r, int buf){
#pragma unroll
    for (int i = 0; i < 4; i++){
      int row = r0 + i * 32;
      u32 w0, w1;
      asm("v_cvt_pk_bf16_f32 %0, %1, %2" : "=v"(w0) : "v"(r[i].x), "v"(r[i].y));
      asm("v_cvt_pk_bf16_f32 %0, %1, %2" : "=v"(w1) : "v"(r[i].z), "v"(r[i].w));
      uint2 o; o.x = w0; o.y = w1;
      *(uint2*)&Ab[buf][row * 64 + ((au ^ (row & 7)) << 3) + ah] = o;
    }
  };

  // ---- B row pointers: wave owns cols wid*64 .. +63; frag = 16B contiguous
  const u16* brow[4];
#pragma unroll
  for (int ni = 0; ni < 4; ni++)
    brow[ni] = WuT + (size_t)(wid * 64 + ni * 16 + l15) * 2048 + g * 8;

  auto computeStep = [&](int buf, int t){
    short8 b0[4], b1[4];
#pragma unroll
    for (int ni = 0; ni < 4; ni++) b0[ni] = *(const short8*)(brow[ni] + (t << 6));
#pragma unroll
    for (int ni = 0; ni < 4; ni++) b1[ni] = *(const short8*)(brow[ni] + (t << 6) + 32);
#pragma unroll
    for (int kh = 0; kh < 2; kh++){
      short8 af[8];
#pragma unroll
      for (int mi = 0; mi < 8; mi++){
        int r = mi * 16 + l15;
        af[mi] = *(const short8*)&Ab[buf][r * 64 + ((((kh << 2) + g) ^ (r & 7)) << 3)];
      }
#pragma unroll
      for (int mi = 0; mi < 8; mi++)
#pragma unroll
        for (int ni = 0; ni < 4; ni++)
          acc[mi][ni] = mfma16(af[mi], kh ? b1[ni] : b0[ni], acc[mi][ni]);
    }
  };

  // ---- main loop: dbuf, one barrier per step
  float4 rS[4];
  issueA(0, rS);
  cvtWriteA(rS, 0);
  __syncthreads();
  int cur = 0;
  for (int t = 0; t < 32; t++){
    float4 rN[4];
    if (t < 31) issueA(t + 1, rN);       // HBM loads land under compute
    computeStep(cur, t);
    if (t < 31) cvtWriteA(rN, cur ^ 1);  // write other buffer (no race w/ cur)
    __syncthreads();
    cur ^= 1;
  }

  // ---- epilogue: score = sum_u tanh(S1+q)*Wv over this wave's 64 cols
#pragma unroll
  for (int mi = 0; mi < 8; mi++){
    int bh = mi >> 2;                     // batch-half (rows 0-63 / 64-127)
#pragma unroll
    for (int j = 0; j < 4; j++){
      float s = 0.f;
#pragma unroll
      for (int ni = 0; ni < 4; ni++){
        int col = wid * 64 + ni * 16 + l15;
        s += tanh_fast(acc[mi][ni][j] + qsl[bh][col]) * wvsl[col];
      }
      s += __shfl_xor(s, 1);
      s += __shfl_xor(s, 2);
      s += __shfl_xor(s, 4);
      s += __shfl_xor(s, 8);
      if (l15 == 0)
        part[mi * 16 + g * 4 + j][wid] = s;
    }
  }
  __syncthreads();
  // in-block softmax: rows 0-63 = batch 2b (wave 0), 64-127 = 2b+1 (wave 1)
  if (tid < 128){
    float s = 0.f;
#pragma unroll
    for (int w = 0; w < 8; w++) s += part[tid][w];
    float mx = s;
#pragma unroll
    for (int m = 32; m >= 1; m >>= 1) mx = fmaxf(mx, __shfl_xor(mx, m));
    float e = __expf(s - mx);
    float sum = e;
#pragma unroll
    for (int m = 32; m >= 1; m >>= 1) sum += __shfl_xor(sum, m);
    attn_out[gm0 + tid] = e / sum;
  }
}

// ---------------------------------------------------------------------------
// ctx[b,:] = sum_l attn[b,l] * FM[b,l,:]  -> x_bf16[b, 0:2048]
__global__ __launch_bounds__(512) void k_ctx(
    const float* __restrict__ fm, const float* __restrict__ attn,
    u16* __restrict__ xbf){
  __shared__ float as_[64];
  int b = blockIdx.x, tid = threadIdx.x;
  if (tid < 64) as_[tid] = attn[(size_t)b * 64 + tid];
  __syncthreads();
  const float4* fmr = (const float4*)(fm + (size_t)b * (64 * 2048));
  float4 cx = {0.f, 0.f, 0.f, 0.f};
#pragma unroll 4
  for (int l = 0; l < 64; l++){
    float a = as_[l];
    float4 v = fmr[(size_t)l * 512 + tid];
    cx.x = fmaf(a, v.x, cx.x); cx.y = fmaf(a, v.y, cx.y);
    cx.z = fmaf(a, v.z, cx.z); cx.w = fmaf(a, v.w, cx.w);
  }
  uint2 o;
  o.x = (u32)f2bf(cx.x) | ((u32)f2bf(cx.y) << 16);
  o.y = (u32)f2bf(cx.z) | ((u32)f2bf(cx.w) << 16);
  *(uint2*)&xbf[(size_t)b * 2304 + tid * 4] = o;
}

// ---------------------------------------------------------------------------
// generic GEMM: C(MxN) = A(MxK bf16) @ Bt(NxK bf16)^T, epilogue scale/offset
template<bool OBF>
__global__ __launch_bounds__(512) void k_gemm(
    const u16* __restrict__ A, const u16* __restrict__ Bt,
    const float* __restrict__ scale, const float* __restrict__ off,
    void* __restrict__ Cout, int K, int N){
  __shared__ __align__(16) u16 Alds[2][128 * 64];
  __shared__ __align__(16) u16 Blds[2][128 * 64];
  int n0 = blockIdx.x << 7, m0 = blockIdx.y << 7;
  int tid = threadIdx.x, wid = tid >> 6, lane = tid & 63;
  int wm = wid >> 2, wn = wid & 3;

  f32x4 acc[4][2];
#pragma unroll
  for (int i = 0; i < 4; i++)
#pragma unroll
    for (int j = 0; j < 2; j++) acc[i][j] = (f32x4){0.f, 0.f, 0.f, 0.f};

  auto stage = [&](int s, int k0){
#pragma unroll
    for (int i = 0; i < 2; i++){
      int p = ((wid * 2 + i) << 6) + lane;
      int row = p >> 3, sl = p & 7, sl2 = sl ^ (row & 7);
      gload16(A  + (size_t)(m0 + row) * K + k0 + sl2 * 8,
              (char*)Alds[s] + (size_t)(wid * 2 + i) * 1024);
      gload16(Bt + (size_t)(n0 + row) * K + k0 + sl2 * 8,
              (char*)Blds[s] + (size_t)(wid * 2 + i) * 1024);
    }
  };

  int nk = K >> 6;
  stage(0, 0);
  __syncthreads();
  int cur = 0;
  for (int t = 0; t < nk; t++){
    if (t + 1 < nk) stage(cur ^ 1, (t + 1) << 6);
#pragma unroll
    for (int kh = 0; kh < 2; kh++){
      short8 af[4], bfr[2];
#pragma unroll
      for (int mi = 0; mi < 4; mi++){
        int r = wm * 64 + mi * 16 + (lane & 15);
        af[mi] = *(const short8*)&Alds[cur][r * 64 + (((kh << 2) + (lane >> 4)) ^ (r & 7)) * 8];
      }
#pragma unroll
      for (int ni = 0; ni < 2; ni++){
        int r = wn * 32 + ni * 16 + (lane & 15);
        bfr[ni] = *(const short8*)&Blds[cur][r * 64 + (((kh << 2) + (lane >> 4)) ^ (r & 7)) * 8];
      }
#pragma unroll
      for (int mi = 0; mi < 4; mi++)
#pragma unroll
        for (int ni = 0; ni < 2; ni++)
          acc[mi][ni] = mfma16(af[mi], bfr[ni], acc[mi][ni]);
    }
    __syncthreads();
    cur ^= 1;
  }
#pragma unroll
  for (int ni = 0; ni < 2; ni++){
    int n = n0 + wn * 32 + ni * 16 + (lane & 15);
    float sc = scale ? scale[n] : 1.f;
    float of = off ? off[n] : 0.f;
#pragma unroll
    for (int mi = 0; mi < 4; mi++)
#pragma unroll
      for (int j = 0; j < 4; j++){
        int m = m0 + wm * 64 + mi * 16 + (lane >> 4) * 4 + j;
        float v = acc[mi][ni][j] * sc + of;
        if (OBF) ((u16*)Cout)[(size_t)m * N + n] = f2bf(v);
        else     ((float*)Cout)[(size_t)m * N + n] = v;
      }
  }
}

// ---------------------------------------------------------------------------
__global__ __launch_bounds__(512) void k_gates(
    const float* __restrict__ xg, const float* __restrict__ gru_b,
    float* __restrict__ hout, u16* __restrict__ hbf){
  int b = blockIdx.x, u = threadIdx.x;
  const float* rg = gru_b + 1536;
  size_t base = (size_t)b * 1536;
  float z  = sigmoidf_(xg[base + u]        + rg[u]);
  float r  = sigmoidf_(xg[base + 512 + u]  + rg[512 + u]);
  float hh = tanh_fast(xg[base + 1024 + u] + r * rg[1024 + u]);
  float h = (1.f - z) * hh;
  hout[(size_t)b * 512 + u] = h;
  hbf[(size_t)b * 512 + u] = f2bf(h);
}

// ---------------------------------------------------------------------------
extern "C" void kernel_launch(void* const* d_in, const int* in_sizes, int n_in,
                              void* d_out, int out_size, void* d_ws, size_t ws_size,
                              hipStream_t stream){
  const int*   tok   = (const int*)  d_in[0];
  const float* fm    = (const float*)d_in[1];
  const float* ps    = (const float*)d_in[2];
  const float* emb   = (const float*)d_in[3];
  const float* Wu    = (const float*)d_in[4];
  const float* bu    = (const float*)d_in[5];
  const float* Ww    = (const float*)d_in[6];
  const float* bw    = (const float*)d_in[7];
  const float* Wv    = (const float*)d_in[8];
  // d_in[9] = bv: softmax-invariant, unused. d_in[11] = gru_rk: dead in reference.
  const float* gru_k = (const float*)d_in[10];
  const float* gru_b = (const float*)d_in[12];
  const float* W1    = (const float*)d_in[13];
  const float* b1    = (const float*)d_in[14];
  const float* gamma = (const float*)d_in[15];
  const float* beta  = (const float*)d_in[16];
  const float* mmean = (const float*)d_in[17];
  const float* mvar  = (const float*)d_in[18];
  const float* W2    = (const float*)d_in[19];
  const float* b2    = (const float*)d_in[20];

  float* logits = (float*)d_out;                     // 1024 x 32000
  float* hout   = (float*)d_out + 32768000;          // 1024 x 512
  float* attn   = (float*)d_out + 33292288;          // 1024 x 64

  char* ws = (char*)d_ws;
  u16*   WuT = (u16*)  (ws + 0);          // 512  x 2048 bf16
  u16*   gkT = (u16*)  (ws + 2097152);    // 1536 x 2304 bf16
  u16*   W2T = (u16*)  (ws + 9175040);    // 32000x 512  bf16
  u16*   W1T = (u16*)  (ws + 41943040);   // 512  x 512  bf16
  float* qws = (float*)(ws + 42467328);   // 1024 x 512  f32
  u16*   xbf = (u16*)  (ws + 44564480);   // 1024 x 2304 bf16
  float* xg  = (float*)(ws + 49283072);   // 1024 x 1536 f32
  u16*   hbf = (u16*)  (ws + 55574528);   // 1024 x 512  bf16
  u16*   ybf = (u16*)  (ws + 56623104);   // 1024 x 512  bf16
  float* bns = (float*)(ws + 57671680);   // 512 f32
  float* bno = (float*)(ws + 57673728);   // 512 f32

  k_transpose_cvt<<<dim3(32, 8),  256, 0, stream>>>(Wu,    WuT, 2048, 512);
  k_transpose_cvt<<<dim3(36, 24), 256, 0, stream>>>(gru_k, gkT, 2304, 1536);
  k_transpose_cvt<<<dim3(8, 500), 256, 0, stream>>>(W2,    W2T, 512,  32000);
  k_transpose_cvt<<<dim3(8, 8),   256, 0, stream>>>(W1,    W1T, 512,  512);
  k_q<<<64, 512, 0, stream>>>(ps, Ww, bw, bu, qws);
  k_gather<<<1024, 256, 0, stream>>>(tok, emb, xbf);
  k_bnprep<<<1, 512, 0, stream>>>(gamma, beta, mmean, mvar, b1, bns, bno);
  // attention: byte-minimal full-N score GEMM (+fused softmax) -> ctx
  k_score<<<512, 512, 0, stream>>>(fm, WuT, qws, Wv, attn);
  k_ctx<<<1024, 512, 0, stream>>>(fm, attn, xbf);
  // xg = x @ gru_k + gru_b[0]
  k_gemm<false><<<dim3(12, 8), 512, 0, stream>>>(xbf, gkT, nullptr, gru_b, xg, 2304, 1536);
  k_gates<<<1024, 512, 0, stream>>>(xg, gru_b, hout, hbf);
  k_gemm<true><<<dim3(4, 8), 512, 0, stream>>>(hbf, W1T, bns, bno, ybf, 512, 512);
  k_gemm<false><<<dim3(250, 8), 512, 0, stream>>>(ybf, W2T, nullptr, b2, logits, 512, 32000);
}